// Round 1
// baseline (314.193 us; speedup 1.0000x reference)
//
#include <hip/hip_runtime.h>

// MCR^2 loss, m x p fp32 x, labels y in [0,K). m=262144, p=128, K=10.
#define K 10
#define P 128
#define EPSV 0.01f
#define GAM1 1.0f
#define GAM2 1.0f
#define CH 256      // rows per gram block (class segments padded to multiple of CH)
#define SK 32       // staged rows (k-depth) per LDS stage
#define KS 36       // LDS k-stride in bf16 elems (32 + 4 pad; 72 B/col keeps b64 aligned)
#define NSTG (CH / SK)
#define SORTCH 2048 // rows per sort block
#define NTHR 256

typedef __attribute__((ext_vector_type(8))) short bf16x8;
typedef __attribute__((ext_vector_type(4))) short s16x4;
typedef __attribute__((ext_vector_type(4))) float f32x4;

static __device__ __forceinline__ short f2bf(float f) {
    unsigned u = __float_as_uint(f);
    u = (u + 0x7FFFu + ((u >> 16) & 1u)) >> 16;   // RNE
    return (short)u;
}

// wave-uniform broadcast from a compile-time-constant lane: pure VALU->SGPR
static __device__ __forceinline__ float rdlane(float v, int srclane) {
    return __int_as_float(__builtin_amdgcn_readlane(__float_as_int(v), srclane));
}

// ---------------- histogram per sort-block ----------------
__global__ void hist_kernel(const int* __restrict__ y, int* __restrict__ blk_counts, int m) {
    __shared__ int h[K];
    int t = threadIdx.x;
    if (t < K) h[t] = 0;
    __syncthreads();
    int base = blockIdx.x * SORTCH;
    int rows = min(SORTCH, m - base);
    for (int i = t; i < rows; i += NTHR) atomicAdd(&h[y[base + i]], 1);
    __syncthreads();
    if (t < K) blk_counts[blockIdx.x * K + t] = h[t];
}

// ---------------- parallel scan of block counts; padded class starts ----------
__global__ void scan_kernel(const int* __restrict__ blk_counts, int* __restrict__ blk_offsets,
                            int* __restrict__ counts, int* __restrict__ pstart, int nb) {
    __shared__ int s[K][128];
    __shared__ int sps[K + 1];
    int t = threadIdx.x;
    int own[K];
    if (t < 128) {
        for (int c = 0; c < K; ++c) {
            int v = (t < nb) ? blk_counts[t * K + c] : 0;
            own[c] = v;
            s[c][t] = v;
        }
    }
    __syncthreads();
    for (int off = 1; off < 128; off <<= 1) {
        int tmp[K];
        if (t < 128)
            for (int c = 0; c < K; ++c) tmp[c] = (t >= off) ? s[c][t - off] : 0;
        __syncthreads();
        if (t < 128)
            for (int c = 0; c < K; ++c) s[c][t] += tmp[c];
        __syncthreads();
    }
    if (t == 0) {
        int run = 0;
        for (int c = 0; c < K; ++c) {
            sps[c] = run;
            int tot = s[c][127];
            counts[c] = tot;
            pstart[c] = run;
            run += ((tot + CH - 1) / CH) * CH;   // pad each class to multiple of CH
        }
        sps[K] = run;
        pstart[K] = run;
    }
    __syncthreads();
    if (t < nb)
        for (int c = 0; c < K; ++c)
            blk_offsets[t * K + c] = sps[c] + s[c][t] - own[c];   // exclusive + padded base
}

// ---------------- scatter row indices into padded class-sorted perm -----------
__global__ void scatter_kernel(const int* __restrict__ y, const int* __restrict__ blk_offsets,
                               int* __restrict__ perm, int m) {
    __shared__ int cur[K];
    int t = threadIdx.x;
    if (t < K) cur[t] = blk_offsets[blockIdx.x * K + t];
    __syncthreads();
    int base = blockIdx.x * SORTCH;
    int rows = min(SORTCH, m - base);
    for (int i = t; i < rows; i += NTHR) {
        int row = base + i;
        int pos = atomicAdd(&cur[y[row]], 1);
        perm[pos] = row;
    }
}

// ---------------- per-class Gram via bf16 MFMA --------------------------------
// v2: CH=256 (1034 blocks, 4/CU), double-buffered LDS, prefetch issued AFTER the
// barrier so the compiler's vmcnt(0) barrier drain never waits on it; one
// barrier per stage. Padded slots guarded via pstart+counts (no perm poison).
__global__ __launch_bounds__(NTHR, 4) void gram_kernel(const float* __restrict__ x,
                                                       const int* __restrict__ perm,
                                                       const int* __restrict__ pstart,
                                                       const int* __restrict__ counts,
                                                       float* __restrict__ grams) {
    __shared__ int pm[CH];
    __shared__ short xsT[2][P * KS];   // 2 x 9216 B
    int t = threadIdx.x;
    int base = blockIdx.x * CH;
    int cls = 0;
#pragma unroll
    for (int c = 1; c < K; ++c)
        if (base >= pstart[c]) cls = c;
    const int limit = pstart[cls] + counts[cls];   // first padded (invalid) position
    pm[t] = perm[base + t];                        // CH == NTHR

    const int lane = t & 63;
    const int wave = t >> 6;
    const int m16 = lane & 15;
    const int quad = lane >> 4;
    const int wr = wave >> 1;   // tile-row half (gram rows wr*64..+64)
    const int wc = wave & 1;    // tile-col half
    const int c2 = lane;        // staging: float2 column pair (cols 2*c2, 2*c2+1)

    f32x4 acc[4][4];
#pragma unroll
    for (int a = 0; a < 4; ++a)
#pragma unroll
        for (int b = 0; b < 4; ++b) acc[a][b] = (f32x4){0.f, 0.f, 0.f, 0.f};

    __syncthreads();   // pm visible

    // prologue: stage 0 into registers (wave w owns rows w*8..w*8+7 of the stage)
    float2 v[8];
#pragma unroll
    for (int ii = 0; ii < 8; ++ii) {
        int pos = wave * 8 + ii;
        float2 val; val.x = 0.f; val.y = 0.f;
        if (base + pos < limit) {
            int r = pm[pos];
            val = ((const float2*)(x + (size_t)r * P))[c2];
        }
        v[ii] = val;
    }

#pragma unroll 2
    for (int s = 0; s < NSTG; ++s) {
        short* xb = &xsT[s & 1][0];
        // ---- convert + write stage s (consumes v) ----
        short b0[8], b1[8];
#pragma unroll
        for (int ii = 0; ii < 8; ++ii) { b0[ii] = f2bf(v[ii].x); b1[ii] = f2bf(v[ii].y); }
        {
            int col0 = 2 * c2, col1 = 2 * c2 + 1;
            int kb = wave * 8;
#pragma unroll
            for (int q = 0; q < 2; ++q) {
                s16x4 w0 = {b0[q * 4], b0[q * 4 + 1], b0[q * 4 + 2], b0[q * 4 + 3]};
                s16x4 w1 = {b1[q * 4], b1[q * 4 + 1], b1[q * 4 + 2], b1[q * 4 + 3]};
                *(s16x4*)&xb[col0 * KS + kb + q * 4] = w0;
                *(s16x4*)&xb[col1 * KS + kb + q * 4] = w1;
            }
        }
        __syncthreads();   // no vmem outstanding here: prior prefetch fully consumed above
        // ---- issue prefetch for stage s+1; lands during the MFMA block ----
        if (s + 1 < NSTG) {
            int sb = (s + 1) * SK;
#pragma unroll
            for (int ii = 0; ii < 8; ++ii) {
                int pos = sb + wave * 8 + ii;
                float2 val; val.x = 0.f; val.y = 0.f;
                if (base + pos < limit) {
                    int r = pm[pos];
                    val = ((const float2*)(x + (size_t)r * P))[c2];
                }
                v[ii] = val;
            }
        }
        // ---- MFMA on stage s ----
        int k0 = quad * 8;
        bf16x8 bfr[4];
#pragma unroll
        for (int b = 0; b < 4; ++b) {
            int colB = wc * 64 + b * 16 + m16;
            union { bf16x8 v8; s16x4 h[2]; } u;
            u.h[0] = *(const s16x4*)&xb[colB * KS + k0];
            u.h[1] = *(const s16x4*)&xb[colB * KS + k0 + 4];
            bfr[b] = u.v8;
        }
#pragma unroll
        for (int a = 0; a < 4; ++a) {
            int colA = wr * 64 + a * 16 + m16;
            union { bf16x8 v8; s16x4 h[2]; } u;
            u.h[0] = *(const s16x4*)&xb[colA * KS + k0];
            u.h[1] = *(const s16x4*)&xb[colA * KS + k0 + 4];
            bf16x8 af = u.v8;
#pragma unroll
            for (int b = 0; b < 4; ++b)
                acc[a][b] = __builtin_amdgcn_mfma_f32_16x16x32_bf16(af, bfr[b], acc[a][b], 0, 0, 0);
        }
    }
    float* g = grams + (size_t)cls * P * P;
#pragma unroll
    for (int a = 0; a < 4; ++a)
#pragma unroll
        for (int b = 0; b < 4; ++b)
#pragma unroll
            for (int r = 0; r < 4; ++r) {
                int gi = wr * 64 + a * 16 + quad * 4 + r;
                int gj = wc * 64 + b * 16 + m16;
                if (gi <= gj) atomicAdd(&g[gi * P + gj], acc[a][b][r]);
            }
}

// ---------------- sum of class grams (removes 10x redundant loads in logdet) --
__global__ void sum_kernel(const float* __restrict__ grams, float* __restrict__ gsum) {
    int idx = blockIdx.x * 256 + threadIdx.x;
    float s = 0.f;
#pragma unroll
    for (int c = 0; c < K; ++c) s += grams[c * P * P + idx];
    gsum[idx] = s;
}

// ---------------- logdet(I + s*G): blocked symmetric LU, NB=32 ----------------
__global__ __launch_bounds__(256, 1) void logdet_kernel(const float* __restrict__ grams,
                                                        const float* __restrict__ gsum,
                                                        const int* __restrict__ counts,
                                                        float* __restrict__ logd, int m) {
    __shared__ float A[P * P];   // 64 KB
    int t = threadIdx.x, b = blockIdx.x;
    float scale;
    if (b == 0) scale = GAM1 * (float)P / ((float)m * EPSV);
    else if (b == 1) scale = (float)P / ((float)m * EPSV);
    else {
        float cnt = (float)counts[b - 2];
        if (cnt < 1.f) cnt = 1.f;
        scale = (float)P / (cnt * EPSV);
    }
    const float* src = (b < 2) ? gsum : (grams + (size_t)(b - 2) * P * P);
    for (int idx = t; idx < P * P; idx += 256) {
        int i = idx >> 7, c = idx & (P - 1);
        int s2 = (i <= c) ? idx : (c * P + i);   // stored upper triangle
        A[idx] = scale * src[s2] + ((i == c) ? 1.f : 0.f);
    }
    __syncthreads();

    const int lane = t & 63;
    const int wid = t >> 6;
    float lsum = 0.f;

    for (int bs = 0; bs < 4; ++bs) {
        const int j0 = bs * 32;
        if (wid == 0) {
            // ---- phase 1: in-register LU of A[j0:j0+32, j0:j0+32], row/lane --
            float a[32];
            if (lane < 32) {
#pragma unroll
                for (int cc = 0; cc < 8; ++cc)
                    *(f32x4*)&a[cc * 4] = *(f32x4*)&A[(j0 + lane) * P + j0 + cc * 4];
            } else {
#pragma unroll
                for (int cc = 0; cc < 32; ++cc) a[cc] = 0.f;
            }
            float myinv = 0.f;
#pragma unroll
            for (int tt = 0; tt < 32; ++tt) {
                float utt = rdlane(a[tt], tt);
                float inv = __builtin_amdgcn_rcpf(utt);
                lsum += __logf(utt);
                if (lane == tt) myinv = inv;
                bool act = (lane < 32) && (lane > tt);
                float lm = act ? a[tt] * inv : 0.f;
                if (act) a[tt] = lm;     // store scaled L entry (needed by phase 2)
#pragma unroll
                for (int k2 = tt + 1; k2 < 32; ++k2) {
                    float utk = rdlane(a[k2], tt);   // SGPR, ~free
                    a[k2] -= lm * utk;
                }
            }
            if (lane < 32) A[(j0 + lane) * P + j0 + lane] = myinv;  // diag := 1/u_jj

            // ---- phase 2: U12 = L11^-1 * A12, column-per-lane ----
            if (bs < 3) {
                int nc = P - j0 - 32;                 // 96, 64, 32
                int c0 = j0 + 32 + lane;
                int c1 = c0 + 64;
                bool v0 = lane < nc;
                bool v1 = lane + 64 < nc;
                int c0a = v0 ? c0 : (j0 + 32);
                int c1a = v1 ? c1 : (j0 + 32);
                float ua[32], ub[32];
#pragma unroll
                for (int j = 0; j < 32; ++j) {
                    ua[j] = A[(j0 + j) * P + c0a];
                    ub[j] = A[(j0 + j) * P + c1a];
                }
#pragma unroll
                for (int j = 0; j < 32; ++j) {
#pragma unroll
                    for (int t2 = 0; t2 < j; ++t2) {
                        float ljt = rdlane(a[t2], j);   // l[j][t2] from lane j
                        ua[j] -= ljt * ua[t2];
                        ub[j] -= ljt * ub[t2];
                    }
                }
#pragma unroll
                for (int j = 0; j < 32; ++j) {
                    if (v0) A[(j0 + j) * P + c0] = ua[j];
                    if (v1) A[(j0 + j) * P + c1] = ub[j];
                }
            }
        }
        __syncthreads();

        if (bs < 3) {
            // ---- SYRK: A22[i][k] -= sum_j U12[j][i] * invd[j] * U12[j][k] ----
            int nc = P - j0 - 32;
            int nt = nc >> 2;
            int ntiles = nt * nt;
            for (int tile = t; tile < ntiles; tile += 256) {
                int ti = tile / nt, tk = tile - ti * nt;
                int i0 = j0 + 32 + ti * 4, k0 = j0 + 32 + tk * 4;
                f32x4 acc0 = {0, 0, 0, 0}, acc1 = {0, 0, 0, 0};
                f32x4 acc2 = {0, 0, 0, 0}, acc3 = {0, 0, 0, 0};
#pragma unroll
                for (int j = 0; j < 32; ++j) {
                    const float* row = &A[(j0 + j) * P];
                    float invd = row[j0 + j];
                    f32x4 ui = *(const f32x4*)&row[i0];
                    f32x4 uk = *(const f32x4*)&row[k0];
                    uk *= invd;
                    acc0 += ui[0] * uk;
                    acc1 += ui[1] * uk;
                    acc2 += ui[2] * uk;
                    acc3 += ui[3] * uk;
                }
                f32x4* r0 = (f32x4*)&A[(i0 + 0) * P + k0];
                f32x4* r1 = (f32x4*)&A[(i0 + 1) * P + k0];
                f32x4* r2 = (f32x4*)&A[(i0 + 2) * P + k0];
                f32x4* r3 = (f32x4*)&A[(i0 + 3) * P + k0];
                *r0 -= acc0; *r1 -= acc1; *r2 -= acc2; *r3 -= acc3;
            }
            __syncthreads();
        }
    }
    if (t == 0) logd[b] = lsum;
}

// ---------------- combine ----------------
__global__ void final_kernel(const float* __restrict__ logd, const int* __restrict__ counts,
                             float* __restrict__ out, int m) {
    if (threadIdx.x == 0 && blockIdx.x == 0) {
        float empi = 0.5f * logd[0];
        float theo = 0.5f * logd[1];
        float comp = 0.f;
        for (int c = 0; c < K; ++c) {
            float cnt = (float)counts[c];
            if (cnt > 0.f) comp += logd[2 + c] * cnt / (float)m;
        }
        comp *= 0.5f;
        out[0] = GAM2 * (-empi) + comp;
        out[1] = empi;
        out[2] = theo;
        out[3] = comp;
    }
}

extern "C" void kernel_launch(void* const* d_in, const int* in_sizes, int n_in,
                              void* d_out, int out_size, void* d_ws, size_t ws_size,
                              hipStream_t stream) {
    const float* x = (const float*)d_in[0];
    const int* y = (const int*)d_in[1];
    int m = in_sizes[1];
    int nbs = (m + SORTCH - 1) / SORTCH;   // 128 sort blocks
    int nbg = (m + CH - 1) / CH + K;       // 1034 gram blocks (covers worst-case padding)

    char* ws = (char*)d_ws;
    float* grams = (float*)ws;                               // K*P*P*4 = 655360
    float* gsum = (float*)(ws + 655360);                     // P*P*4 = 65536
    float* logd = (float*)(ws + 720896);                     // 12 floats
    int* counts = (int*)(ws + 720960);                       // 10 ints
    int* pstart = (int*)(ws + 721024);                       // 11 ints
    int* blk_counts = (int*)(ws + 721152);                   // nbs*K
    int* blk_offsets = (int*)(ws + 721152 + (size_t)nbs * K * 4);
    int* perm = (int*)(ws + 721152 + 2 * (size_t)nbs * K * 4);   // nbg*CH ints

    hipMemsetAsync(ws, 0, 655360, stream);   // grams (atomic-accumulated); perm needs no poison

    hist_kernel<<<nbs, NTHR, 0, stream>>>(y, blk_counts, m);
    scan_kernel<<<1, NTHR, 0, stream>>>(blk_counts, blk_offsets, counts, pstart, nbs);
    scatter_kernel<<<nbs, NTHR, 0, stream>>>(y, blk_offsets, perm, m);
    gram_kernel<<<nbg, NTHR, 0, stream>>>(x, perm, pstart, counts, grams);
    sum_kernel<<<P * P / 256, 256, 0, stream>>>(grams, gsum);
    logdet_kernel<<<K + 2, 256, 0, stream>>>(grams, gsum, counts, logd, m);
    final_kernel<<<1, 1, 0, stream>>>(logd, counts, (float*)d_out, m);
}

// Round 3
// 303.215 us; speedup vs baseline: 1.0362x; 1.0362x over previous
//
#include <hip/hip_runtime.h>

// MCR^2 loss, m x p fp32 x, labels y in [0,K). m=262144, p=128, K=10.
#define K 10
#define P 128
#define EPSV 0.01f
#define GAM1 1.0f
#define GAM2 1.0f
#define CH 512      // rows per gram block (class segments padded to multiple of CH)
#define SK 64       // staged rows (k-depth) per LDS stage
#define KS 68       // LDS k-stride in bf16 elems (64 + 4 pad)
#define NSTG (CH / SK)   // 8
#define SORTCH 2048 // rows per sort block
#define NTHR 256
#define GTHR 512    // gram kernel threads (8 waves, 32x64 tile each)

typedef __attribute__((ext_vector_type(8))) short bf16x8;
typedef __attribute__((ext_vector_type(4))) short s16x4;
typedef __attribute__((ext_vector_type(4))) float f32x4;

static __device__ __forceinline__ short f2bf(float f) {
    unsigned u = __float_as_uint(f);
    u = (u + 0x7FFFu + ((u >> 16) & 1u)) >> 16;   // RNE
    return (short)u;
}

// wave-uniform broadcast from a compile-time-constant lane: pure VALU->SGPR
static __device__ __forceinline__ float rdlane(float v, int srclane) {
    return __int_as_float(__builtin_amdgcn_readlane(__float_as_int(v), srclane));
}

// ---------------- histogram per sort-block ----------------
__global__ void hist_kernel(const int* __restrict__ y, int* __restrict__ blk_counts, int m) {
    __shared__ int h[K];
    int t = threadIdx.x;
    if (t < K) h[t] = 0;
    __syncthreads();
    int base = blockIdx.x * SORTCH;
    int rows = min(SORTCH, m - base);
    for (int i = t; i < rows; i += NTHR) atomicAdd(&h[y[base + i]], 1);
    __syncthreads();
    if (t < K) blk_counts[blockIdx.x * K + t] = h[t];
}

// ---------------- parallel scan of block counts; padded class starts ----------
__global__ void scan_kernel(const int* __restrict__ blk_counts, int* __restrict__ blk_offsets,
                            int* __restrict__ counts, int* __restrict__ pstart, int nb) {
    __shared__ int s[K][128];
    __shared__ int sps[K + 1];
    int t = threadIdx.x;
    int own[K];
    if (t < 128) {
        for (int c = 0; c < K; ++c) {
            int v = (t < nb) ? blk_counts[t * K + c] : 0;
            own[c] = v;
            s[c][t] = v;
        }
    }
    __syncthreads();
    for (int off = 1; off < 128; off <<= 1) {
        int tmp[K];
        if (t < 128)
            for (int c = 0; c < K; ++c) tmp[c] = (t >= off) ? s[c][t - off] : 0;
        __syncthreads();
        if (t < 128)
            for (int c = 0; c < K; ++c) s[c][t] += tmp[c];
        __syncthreads();
    }
    if (t == 0) {
        int run = 0;
        for (int c = 0; c < K; ++c) {
            sps[c] = run;
            int tot = s[c][127];
            counts[c] = tot;
            pstart[c] = run;
            run += ((tot + CH - 1) / CH) * CH;   // pad each class to multiple of CH
        }
        sps[K] = run;
        pstart[K] = run;
    }
    __syncthreads();
    if (t < nb)
        for (int c = 0; c < K; ++c)
            blk_offsets[t * K + c] = sps[c] + s[c][t] - own[c];   // exclusive + padded base
}

// ---------------- scatter row indices into padded class-sorted perm -----------
__global__ void scatter_kernel(const int* __restrict__ y, const int* __restrict__ blk_offsets,
                               int* __restrict__ perm, int m) {
    __shared__ int cur[K];
    int t = threadIdx.x;
    if (t < K) cur[t] = blk_offsets[blockIdx.x * K + t];
    __syncthreads();
    int base = blockIdx.x * SORTCH;
    int rows = min(SORTCH, m - base);
    for (int i = t; i < rows; i += NTHR) {
        int row = base + i;
        int pos = atomicAdd(&cur[y[row]], 1);
        perm[pos] = row;
    }
}

// ---------------- per-class Gram via bf16 MFMA --------------------------------
// NO atomics: each block streams a full 128x128 fp32 partial to its own
// workspace slot (the R1 regression was 8.5M write-through atomic RMWs to HBM).
// 8 waves/block, 32x64 tile each; 2 blocks/CU (16 waves/CU, 128-VGPR cap).
// Double-buffered LDS, prefetch issued after the barrier, one barrier/stage.
// Padded slots guarded via pstart+counts (perm never poisoned, garbage unread).
__global__ __launch_bounds__(GTHR, 4) void gram_kernel(const float* __restrict__ x,
                                                       const int* __restrict__ perm,
                                                       const int* __restrict__ pstart,
                                                       const int* __restrict__ counts,
                                                       float* __restrict__ partial) {
    __shared__ int pm[CH];
    __shared__ short xsT[2][P * KS];   // 2 x 17408 B
    int t = threadIdx.x;
    int base = blockIdx.x * CH;
    int cls = 0;
#pragma unroll
    for (int c = 1; c < K; ++c)
        if (base >= pstart[c]) cls = c;
    const int limit = pstart[cls] + counts[cls];   // first padded (invalid) position
    pm[t] = perm[base + t];                        // CH == GTHR

    const int lane = t & 63;
    const int wave = t >> 6;    // 0..7
    const int m16 = lane & 15;
    const int quad = lane >> 4;
    const int wr = wave >> 1;   // gram rows wr*32..+32
    const int wc = wave & 1;    // gram cols wc*64..+64
    const int c2 = lane;        // staging: float2 column pair (cols 2*c2, 2*c2+1)

    f32x4 acc[2][4];
#pragma unroll
    for (int a = 0; a < 2; ++a)
#pragma unroll
        for (int b = 0; b < 4; ++b) acc[a][b] = (f32x4){0.f, 0.f, 0.f, 0.f};

    __syncthreads();   // pm visible

    // prologue: stage 0 (wave w owns staged k-rows w*8..w*8+7)
    float2 v[8];
#pragma unroll
    for (int ii = 0; ii < 8; ++ii) {
        int pos = wave * 8 + ii;
        float2 val; val.x = 0.f; val.y = 0.f;
        if (base + pos < limit) {
            int r = pm[pos];
            val = ((const float2*)(x + (size_t)r * P))[c2];
        }
        v[ii] = val;
    }

    for (int s = 0; s < NSTG; ++s) {
        short* xb = &xsT[s & 1][0];
        // ---- convert + write stage s (consumes v) ----
        short b0[8], b1[8];
#pragma unroll
        for (int ii = 0; ii < 8; ++ii) { b0[ii] = f2bf(v[ii].x); b1[ii] = f2bf(v[ii].y); }
        {
            int col0 = 2 * c2, col1 = col0 + 1;
            int kb = wave * 8;
#pragma unroll
            for (int q = 0; q < 2; ++q) {
                s16x4 w0 = {b0[q * 4], b0[q * 4 + 1], b0[q * 4 + 2], b0[q * 4 + 3]};
                s16x4 w1 = {b1[q * 4], b1[q * 4 + 1], b1[q * 4 + 2], b1[q * 4 + 3]};
                *(s16x4*)&xb[col0 * KS + kb + q * 4] = w0;
                *(s16x4*)&xb[col1 * KS + kb + q * 4] = w1;
            }
        }
        __syncthreads();
        // ---- issue prefetch for stage s+1; hides under the MFMA block ----
        if (s + 1 < NSTG) {
            int sb = (s + 1) * SK;
#pragma unroll
            for (int ii = 0; ii < 8; ++ii) {
                int pos = sb + wave * 8 + ii;
                float2 val; val.x = 0.f; val.y = 0.f;
                if (base + pos < limit) {
                    int r = pm[pos];
                    val = ((const float2*)(x + (size_t)r * P))[c2];
                }
                v[ii] = val;
            }
        }
        // ---- MFMA on stage s ----
#pragma unroll
        for (int kk = 0; kk < 2; ++kk) {
            int k0 = kk * 32 + quad * 8;
            bf16x8 bfr[4];
#pragma unroll
            for (int b = 0; b < 4; ++b) {
                int colB = wc * 64 + b * 16 + m16;
                union { bf16x8 v8; s16x4 h[2]; } u;
                u.h[0] = *(const s16x4*)&xb[colB * KS + k0];
                u.h[1] = *(const s16x4*)&xb[colB * KS + k0 + 4];
                bfr[b] = u.v8;
            }
#pragma unroll
            for (int a = 0; a < 2; ++a) {
                int colA = wr * 32 + a * 16 + m16;
                union { bf16x8 v8; s16x4 h[2]; } u;
                u.h[0] = *(const s16x4*)&xb[colA * KS + k0];
                u.h[1] = *(const s16x4*)&xb[colA * KS + k0 + 4];
                bf16x8 af = u.v8;
#pragma unroll
                for (int b = 0; b < 4; ++b)
                    acc[a][b] = __builtin_amdgcn_mfma_f32_16x16x32_bf16(af, bfr[b], acc[a][b], 0, 0, 0);
            }
        }
    }
    // ---- stream full 32x64 tile partial (no atomics) ----
    float* pt = partial + (size_t)blockIdx.x * (P * P);
#pragma unroll
    for (int a = 0; a < 2; ++a)
#pragma unroll
        for (int b = 0; b < 4; ++b)
#pragma unroll
            for (int r = 0; r < 4; ++r) {
                int gi = wr * 32 + a * 16 + quad * 4 + r;
                int gj = wc * 64 + b * 16 + m16;
                pt[gi * P + gj] = acc[a][b][r];
            }
}

// ---------------- per-class reduction of block partials -----------------------
__global__ void reduce_kernel(const float* __restrict__ partial, const int* __restrict__ pstart,
                              float* __restrict__ grams) {
    int c = blockIdx.x >> 6;                       // 64 blocks per class (P*P/256)
    int e = ((blockIdx.x & 63) << 8) + threadIdx.x;
    int b0 = pstart[c] / CH;
    int b1 = pstart[c + 1] / CH;
    float s = 0.f;
    for (int b = b0; b < b1; ++b) s += partial[(size_t)b * (P * P) + e];
    grams[(size_t)c * (P * P) + e] = s;            // fully overwrites grams (no memset needed)
}

// ---------------- sum of class grams (removes 10x redundant loads in logdet) --
__global__ void sum_kernel(const float* __restrict__ grams, float* __restrict__ gsum) {
    int idx = blockIdx.x * 256 + threadIdx.x;
    float s = 0.f;
#pragma unroll
    for (int c = 0; c < K; ++c) s += grams[c * P * P + idx];
    gsum[idx] = s;
}

// ---------------- logdet(I + s*G): blocked symmetric LU, NB=32 ----------------
__global__ __launch_bounds__(256, 1) void logdet_kernel(const float* __restrict__ grams,
                                                        const float* __restrict__ gsum,
                                                        const int* __restrict__ counts,
                                                        float* __restrict__ logd, int m) {
    __shared__ float A[P * P];   // 64 KB
    int t = threadIdx.x, b = blockIdx.x;
    float scale;
    if (b == 0) scale = GAM1 * (float)P / ((float)m * EPSV);
    else if (b == 1) scale = (float)P / ((float)m * EPSV);
    else {
        float cnt = (float)counts[b - 2];
        if (cnt < 1.f) cnt = 1.f;
        scale = (float)P / (cnt * EPSV);
    }
    const float* src = (b < 2) ? gsum : (grams + (size_t)(b - 2) * P * P);
    for (int idx = t; idx < P * P; idx += 256) {
        int i = idx >> 7, c = idx & (P - 1);
        int s2 = (i <= c) ? idx : (c * P + i);   // read upper triangle
        A[idx] = scale * src[s2] + ((i == c) ? 1.f : 0.f);
    }
    __syncthreads();

    const int lane = t & 63;
    const int wid = t >> 6;
    float lsum = 0.f;

    for (int bs = 0; bs < 4; ++bs) {
        const int j0 = bs * 32;
        if (wid == 0) {
            // ---- phase 1: in-register LU of A[j0:j0+32, j0:j0+32], row/lane --
            float a[32];
            if (lane < 32) {
#pragma unroll
                for (int cc = 0; cc < 8; ++cc)
                    *(f32x4*)&a[cc * 4] = *(f32x4*)&A[(j0 + lane) * P + j0 + cc * 4];
            } else {
#pragma unroll
                for (int cc = 0; cc < 32; ++cc) a[cc] = 0.f;
            }
            float myinv = 0.f;
#pragma unroll
            for (int tt = 0; tt < 32; ++tt) {
                float utt = rdlane(a[tt], tt);
                float inv = __builtin_amdgcn_rcpf(utt);
                lsum += __logf(utt);
                if (lane == tt) myinv = inv;
                bool act = (lane < 32) && (lane > tt);
                float lm = act ? a[tt] * inv : 0.f;
                if (act) a[tt] = lm;     // store scaled L entry (needed by phase 2)
#pragma unroll
                for (int k2 = tt + 1; k2 < 32; ++k2) {
                    float utk = rdlane(a[k2], tt);   // SGPR, ~free
                    a[k2] -= lm * utk;
                }
            }
            if (lane < 32) A[(j0 + lane) * P + j0 + lane] = myinv;  // diag := 1/u_jj

            // ---- phase 2: U12 = L11^-1 * A12, column-per-lane ----
            if (bs < 3) {
                int nc = P - j0 - 32;                 // 96, 64, 32
                int c0 = j0 + 32 + lane;
                int c1 = c0 + 64;
                bool v0 = lane < nc;
                bool v1 = lane + 64 < nc;
                int c0a = v0 ? c0 : (j0 + 32);
                int c1a = v1 ? c1 : (j0 + 32);
                float ua[32], ub[32];
#pragma unroll
                for (int j = 0; j < 32; ++j) {
                    ua[j] = A[(j0 + j) * P + c0a];
                    ub[j] = A[(j0 + j) * P + c1a];
                }
#pragma unroll
                for (int j = 0; j < 32; ++j) {
#pragma unroll
                    for (int t2 = 0; t2 < j; ++t2) {
                        float ljt = rdlane(a[t2], j);   // l[j][t2] from lane j
                        ua[j] -= ljt * ua[t2];
                        ub[j] -= ljt * ub[t2];
                    }
                }
#pragma unroll
                for (int j = 0; j < 32; ++j) {
                    if (v0) A[(j0 + j) * P + c0] = ua[j];
                    if (v1) A[(j0 + j) * P + c1] = ub[j];
                }
            }
        }
        __syncthreads();

        if (bs < 3) {
            // ---- SYRK: A22[i][k] -= sum_j U12[j][i] * invd[j] * U12[j][k] ----
            int nc = P - j0 - 32;
            int nt = nc >> 2;
            int ntiles = nt * nt;
            for (int tile = t; tile < ntiles; tile += 256) {
                int ti = tile / nt, tk = tile - ti * nt;
                int i0 = j0 + 32 + ti * 4, k0 = j0 + 32 + tk * 4;
                f32x4 acc0 = {0, 0, 0, 0}, acc1 = {0, 0, 0, 0};
                f32x4 acc2 = {0, 0, 0, 0}, acc3 = {0, 0, 0, 0};
#pragma unroll
                for (int j = 0; j < 32; ++j) {
                    const float* row = &A[(j0 + j) * P];
                    float invd = row[j0 + j];
                    f32x4 ui = *(const f32x4*)&row[i0];
                    f32x4 uk = *(const f32x4*)&row[k0];
                    uk *= invd;
                    acc0 += ui[0] * uk;
                    acc1 += ui[1] * uk;
                    acc2 += ui[2] * uk;
                    acc3 += ui[3] * uk;
                }
                f32x4* r0 = (f32x4*)&A[(i0 + 0) * P + k0];
                f32x4* r1 = (f32x4*)&A[(i0 + 1) * P + k0];
                f32x4* r2 = (f32x4*)&A[(i0 + 2) * P + k0];
                f32x4* r3 = (f32x4*)&A[(i0 + 3) * P + k0];
                *r0 -= acc0; *r1 -= acc1; *r2 -= acc2; *r3 -= acc3;
            }
            __syncthreads();
        }
    }
    if (t == 0) logd[b] = lsum;
}

// ---------------- combine ----------------
__global__ void final_kernel(const float* __restrict__ logd, const int* __restrict__ counts,
                             float* __restrict__ out, int m) {
    if (threadIdx.x == 0 && blockIdx.x == 0) {
        float empi = 0.5f * logd[0];
        float theo = 0.5f * logd[1];
        float comp = 0.f;
        for (int c = 0; c < K; ++c) {
            float cnt = (float)counts[c];
            if (cnt > 0.f) comp += logd[2 + c] * cnt / (float)m;
        }
        comp *= 0.5f;
        out[0] = GAM2 * (-empi) + comp;
        out[1] = empi;
        out[2] = theo;
        out[3] = comp;
    }
}

extern "C" void kernel_launch(void* const* d_in, const int* in_sizes, int n_in,
                              void* d_out, int out_size, void* d_ws, size_t ws_size,
                              hipStream_t stream) {
    const float* x = (const float*)d_in[0];
    const int* y = (const int*)d_in[1];
    int m = in_sizes[1];
    int nbs = (m + SORTCH - 1) / SORTCH;   // 128 sort blocks
    int nbg = (m + CH - 1) / CH + K;       // 522 gram blocks (covers worst-case padding)

    char* ws = (char*)d_ws;
    float* grams = (float*)ws;                               // K*P*P*4 = 655360
    float* gsum = (float*)(ws + 655360);                     // P*P*4 = 65536
    float* logd = (float*)(ws + 720896);                     // 12 floats
    int* counts = (int*)(ws + 720960);                       // 10 ints
    int* pstart = (int*)(ws + 721024);                       // 11 ints
    int* blk_counts = (int*)(ws + 721152);                   // nbs*K
    int* blk_offsets = (int*)(ws + 721152 + (size_t)nbs * K * 4);
    int* perm = (int*)(ws + 721152 + 2 * (size_t)nbs * K * 4);   // nbg*CH ints (~1.07 MB)
    float* partial = (float*)(ws + (2u << 20));              // nbg*P*P*4 = 34.2 MB (ws is 512 MiB)

    // no memsets: perm padding guarded via pstart+counts; grams overwritten by reduce

    hist_kernel<<<nbs, NTHR, 0, stream>>>(y, blk_counts, m);
    scan_kernel<<<1, NTHR, 0, stream>>>(blk_counts, blk_offsets, counts, pstart, nbs);
    scatter_kernel<<<nbs, NTHR, 0, stream>>>(y, blk_offsets, perm, m);
    gram_kernel<<<nbg, GTHR, 0, stream>>>(x, perm, pstart, counts, partial);
    reduce_kernel<<<K * (P * P / 256), 256, 0, stream>>>(partial, pstart, grams);
    sum_kernel<<<P * P / 256, 256, 0, stream>>>(grams, gsum);
    logdet_kernel<<<K + 2, 256, 0, stream>>>(grams, gsum, counts, logd, m);
    final_kernel<<<1, 1, 0, stream>>>(logd, counts, (float*)d_out, m);
}